// Round 1
// baseline (156.948 us; speedup 1.0000x reference)
//
#include <hip/hip_runtime.h>
#include <math.h>

#define BB 32
#define NN 200
#define DD 100
#define NEGV (-9e15f)
#define SLOPE 0.2f

// One block per (b, i). 256 threads.
__global__ __launch_bounds__(256) void gat_agg_kernel(
    const int*   __restrict__ inputs,   // [B,N]
    const int*   __restrict__ adj,      // [B,N,N]
    const float* __restrict__ emb,      // [V,D]
    const float* __restrict__ a0,       // [D]
    const float* __restrict__ a1,
    const float* __restrict__ a2,
    const float* __restrict__ a3,
    float*       __restrict__ out)      // [B,N,D]
{
    const int bi  = blockIdx.x;        // b*N + i
    const int b   = bi / NN;
    const int tid = threadIdx.x;

    __shared__ float gi[4][DD];        // h_i * a_k, k=0..3
    __shared__ float sj[NN];           // scores -> exp(s - m)
    __shared__ int   sidx[NN];         // emb row index per neighbor j
    __shared__ float part[DD];         // phase-D partial
    __shared__ float red[2];           // [0]=max, [1]=1/sum

    // ---- Phase A: stage indices + scaled query rows ----
    if (tid < NN) sidx[tid] = inputs[b * NN + tid];

    const int idx_i = inputs[bi];      // uniform -> scalar load
    for (int t = tid; t < 4 * DD; t += 256) {
        const int k = t / DD;
        const int d = t - k * DD;
        const float* ak = (k == 0) ? a0 : (k == 1) ? a1 : (k == 2) ? a2 : a3;
        gi[k][d] = emb[idx_i * DD + d] * ak[d];
    }
    __syncthreads();

    // ---- Phase B: selected edge score per neighbor j = tid ----
    if (tid < NN) {
        float s = NEGV;
        const int k = adj[(long)bi * NN + tid];   // adj[b][i][j]
        if (k >= 1 && k <= 4) {
            const float4* hj = reinterpret_cast<const float4*>(emb + (long)sidx[tid] * DD);
            const float4* gk = reinterpret_cast<const float4*>(gi[k - 1]);
            float ax = 0.f, ay = 0.f, az = 0.f, aw = 0.f;
            #pragma unroll
            for (int q = 0; q < DD / 4; ++q) {
                const float4 hv = hj[q];
                const float4 gv = gk[q];
                ax += hv.x * gv.x; ay += hv.y * gv.y;
                az += hv.z * gv.z; aw += hv.w * gv.w;
            }
            s = (ax + ay) + (az + aw);
            s = (s >= 0.f) ? s : SLOPE * s;
        }
        sj[tid] = s;
    }
    __syncthreads();

    // ---- Phase C: softmax over j (wave-0 reductions) ----
    if (tid < 64) {
        float m = -INFINITY;
        for (int j = tid; j < NN; j += 64) m = fmaxf(m, sj[j]);
        #pragma unroll
        for (int off = 32; off >= 1; off >>= 1)
            m = fmaxf(m, __shfl_down(m, off, 64));
        if (tid == 0) red[0] = m;
    }
    __syncthreads();
    const float m = red[0];
    if (tid < NN) sj[tid] = __expf(sj[tid] - m);
    __syncthreads();
    if (tid < 64) {
        float sum = 0.f;
        for (int j = tid; j < NN; j += 64) sum += sj[j];
        #pragma unroll
        for (int off = 32; off >= 1; off >>= 1)
            sum += __shfl_down(sum, off, 64);
        if (tid == 0) red[1] = 1.0f / sum;
    }
    __syncthreads();
    const float inv = red[1];

    // ---- Phase D: out[b,i,d] = inv * sum_j e_j * h[j,d] ----
    // 200 threads: d = tid % 100, segment = tid / 100 covers half the j range.
    float acc = 0.f;
    const int d   = (tid < 2 * DD) ? (tid % DD) : 0;
    const int seg = tid / DD;
    if (tid < 2 * DD) {
        const int j0 = seg * (NN / 2);
        #pragma unroll 4
        for (int j = j0; j < j0 + NN / 2; ++j) {
            acc += sj[j] * emb[(long)sidx[j] * DD + d];
        }
    }
    __syncthreads();
    if (tid >= DD && tid < 2 * DD) part[d] = acc;
    __syncthreads();
    if (tid < DD) out[(long)bi * DD + tid] = (acc + part[tid]) * inv;
}

extern "C" void kernel_launch(void* const* d_in, const int* in_sizes, int n_in,
                              void* d_out, int out_size, void* d_ws, size_t ws_size,
                              hipStream_t stream) {
    const int*   inputs = (const int*)  d_in[0];   // [B,N]
    const int*   adj    = (const int*)  d_in[1];   // [B,N,N]
    // d_in[2] = mask_item (unused: all ones, eval mode)
    const float* emb    = (const float*)d_in[3];   // [V,D]
    const float* a0     = (const float*)d_in[4];
    const float* a1     = (const float*)d_in[5];
    const float* a2     = (const float*)d_in[6];
    const float* a3     = (const float*)d_in[7];
    float*       out    = (float*)d_out;           // [B,N,D]

    dim3 grid(BB * NN);
    dim3 block(256);
    gat_agg_kernel<<<grid, block, 0, stream>>>(inputs, adj, emb, a0, a1, a2, a3, out);
}

// Round 2
// 111.286 us; speedup vs baseline: 1.4103x; 1.4103x over previous
//
#include <hip/hip_runtime.h>
#include <math.h>

#define NEGV (-9e15f)
#define SLOPE 0.2f

// Grid: 256 blocks = (b in 0..31) x (itile in 0..7); block covers i = itile*25 .. +24.
// 256 threads. LDS: G (h_i * a_k) 40KB + ST (scores, transposed [j][i]) 22.4KB + sidx.
__global__ __launch_bounds__(256, 1) void gat_tile_kernel(
    const int*   __restrict__ inputs,   // [32,200]
    const int*   __restrict__ adj,      // [32,200,200]
    const float* __restrict__ emb,      // [V,100]
    const float* __restrict__ a0, const float* __restrict__ a1,
    const float* __restrict__ a2, const float* __restrict__ a3,
    float*       __restrict__ out)      // [32,200,100]
{
    const int b   = blockIdx.x >> 3;
    const int i0  = (blockIdx.x & 7) * 25;
    const int tid = threadIdx.x;

    __shared__ int   sidx[200];        // emb row per session position
    __shared__ float G[25][4][100];    // h_{i0+i} * a_k
    __shared__ float ST[200][28];      // scores/weights, [j][i] (row 112B, 16B-aligned)

    if (tid < 200) sidx[tid] = inputs[b * 200 + tid];
    __syncthreads();

    const float4* embv = (const float4*)emb;

    // ---- Fill G: G[i][k][:] = emb[sidx[i0+i]] * a_k ----
    for (int t = tid; t < 25 * 25; t += 256) {
        const int i = t / 25, dc = t % 25;
        const float4 hv = embv[(size_t)sidx[i0 + i] * 25 + dc];
        const float4 av0 = ((const float4*)a0)[dc];
        const float4 av1 = ((const float4*)a1)[dc];
        const float4 av2 = ((const float4*)a2)[dc];
        const float4 av3 = ((const float4*)a3)[dc];
        float4 g;
        g.x=hv.x*av0.x; g.y=hv.y*av0.y; g.z=hv.z*av0.z; g.w=hv.w*av0.w;
        ((float4*)&G[i][0][0])[dc] = g;
        g.x=hv.x*av1.x; g.y=hv.y*av1.y; g.z=hv.z*av1.z; g.w=hv.w*av1.w;
        ((float4*)&G[i][1][0])[dc] = g;
        g.x=hv.x*av2.x; g.y=hv.y*av2.y; g.z=hv.z*av2.z; g.w=hv.w*av2.w;
        ((float4*)&G[i][2][0])[dc] = g;
        g.x=hv.x*av3.x; g.y=hv.y*av3.y; g.z=hv.z*av3.z; g.w=hv.w*av3.w;
        ((float4*)&G[i][3][0])[dc] = g;
    }

    // ---- Load h_j into registers + prefetch adj column (independent of G) ----
    float4 h[25];
    int    kv[25];
    if (tid < 200) {
        const size_t hb = (size_t)sidx[tid] * 25;
        #pragma unroll
        for (int c = 0; c < 25; ++c) h[c] = embv[hb + c];
        const int arow = (b * 200 + i0) * 200 + tid;
        #pragma unroll
        for (int i = 0; i < 25; ++i) kv[i] = adj[arow + i * 200];
    }
    __syncthreads();   // G ready

    // ---- Score pass: thread j computes selected-k score vs each of 25 i ----
    if (tid < 200) {
        for (int i = 0; i < 25; ++i) {
            const int k  = kv[i];
            const int kk = (k - 1) & 3;            // any valid row when k==0
            const float4* Gv = (const float4*)&G[i][kk][0];
            float ax = 0.f, ay = 0.f, az = 0.f, aw = 0.f;
            #pragma unroll
            for (int c = 0; c < 25; ++c) {
                const float4 gv = Gv[c];
                ax += gv.x * h[c].x; ay += gv.y * h[c].y;
                az += gv.z * h[c].z; aw += gv.w * h[c].w;
            }
            float s = (ax + ay) + (az + aw);
            s = (s >= 0.f) ? s : SLOPE * s;
            ST[tid][i] = (k >= 1 && k <= 4) ? s : NEGV;
        }
    }
    __syncthreads();

    // ---- Softmax per i-row: 8 lanes per row, width-8 shuffles ----
    {
        const int r = tid >> 3, l = tid & 7;       // r = local i, l = lane in group
        if (r < 25) {
            float m = -INFINITY;
            #pragma unroll
            for (int t = 0; t < 25; ++t) m = fmaxf(m, ST[l + 8 * t][r]);
            #pragma unroll
            for (int off = 4; off >= 1; off >>= 1) m = fmaxf(m, __shfl_xor(m, off, 8));
            float e[25];
            float sum = 0.f;
            #pragma unroll
            for (int t = 0; t < 25; ++t) {
                e[t] = __expf(ST[l + 8 * t][r] - m);
                sum += e[t];
            }
            #pragma unroll
            for (int off = 4; off >= 1; off >>= 1) sum += __shfl_xor(sum, off, 8);
            const float inv = 1.0f / sum;
            #pragma unroll
            for (int t = 0; t < 25; ++t) ST[l + 8 * t][r] = e[t] * inv;
        }
    }
    __syncthreads();

    // ---- Aggregation: thread (ig = tid&7, dc = tid>>3) covers j-segment ig,
    //      d-chunk dc; accumulates all 25 i outputs; shfl-reduce over ig. ----
    {
        const int ig = tid & 7;
        const int dc = tid >> 3;                   // 0..31, active < 25
        float4 acc[25];
        #pragma unroll
        for (int i = 0; i < 25; ++i) { acc[i].x = 0.f; acc[i].y = 0.f; acc[i].z = 0.f; acc[i].w = 0.f; }
        if (dc < 25) {
            for (int jj = 0; jj < 25; ++jj) {
                const int j = ig * 25 + jj;
                float4 w4[7];
                #pragma unroll
                for (int c = 0; c < 7; ++c) w4[c] = ((const float4*)&ST[j][0])[c];
                const float* w = (const float*)w4;
                const float4 hv = embv[(size_t)sidx[j] * 25 + dc];
                #pragma unroll
                for (int i = 0; i < 25; ++i) {
                    acc[i].x += w[i] * hv.x; acc[i].y += w[i] * hv.y;
                    acc[i].z += w[i] * hv.z; acc[i].w += w[i] * hv.w;
                }
            }
        }
        #pragma unroll
        for (int i = 0; i < 25; ++i) {
            #pragma unroll
            for (int off = 1; off <= 4; off <<= 1) {
                acc[i].x += __shfl_xor(acc[i].x, off, 64);
                acc[i].y += __shfl_xor(acc[i].y, off, 64);
                acc[i].z += __shfl_xor(acc[i].z, off, 64);
                acc[i].w += __shfl_xor(acc[i].w, off, 64);
            }
        }
        if (ig == 0 && dc < 25) {
            #pragma unroll
            for (int i = 0; i < 25; ++i)
                ((float4*)out)[(size_t)(b * 200 + i0 + i) * 25 + dc] = acc[i];
        }
    }
}

extern "C" void kernel_launch(void* const* d_in, const int* in_sizes, int n_in,
                              void* d_out, int out_size, void* d_ws, size_t ws_size,
                              hipStream_t stream) {
    const int*   inputs = (const int*)  d_in[0];
    const int*   adj    = (const int*)  d_in[1];
    // d_in[2] = mask_item (all ones, unused)
    const float* emb    = (const float*)d_in[3];
    const float* a0     = (const float*)d_in[4];
    const float* a1     = (const float*)d_in[5];
    const float* a2     = (const float*)d_in[6];
    const float* a3     = (const float*)d_in[7];
    float*       out    = (float*)d_out;

    gat_tile_kernel<<<dim3(256), dim3(256), 0, stream>>>(inputs, adj, emb, a0, a1, a2, a3, out);
}